// Round 1
// baseline (661.519 us; speedup 1.0000x reference)
//
#include <hip/hip_runtime.h>

#define EPSF 1e-12f
#define NT1 512

// ---------------------------------------------------------------------------
// Kernel 1: fused  t = w_in@x  -> depthwise 3x3 -> gate -> q,v
//           v written to global (d_out used as scratch), G=q.v^T, |q|^2, |v|^2
//           accumulated in registers across tiles, atomically flushed.
// Grid: 256 blocks (64 per batch), 512 threads. Each block: 16 8x8 tiles.
// ---------------------------------------------------------------------------
__global__ __launch_bounds__(NT1)
void k1_fused(const float* __restrict__ x, const float* __restrict__ w_in,
              const float* __restrict__ w_dw, float* __restrict__ v_out,
              float* __restrict__ Gacc, float* __restrict__ sqq,
              float* __restrict__ sqv)
{
    // LDS: 65536 + 5632 + 26624 + 26880 + 33792 = 158464 B  (<= 160 KiB)
    __shared__ __attribute__((aligned(16))) float wT[64][256];    // w_in transposed [c][och]
    __shared__ __attribute__((aligned(16))) float wdw_s[128][11]; // stride 11: gcd(11,32)=1
    __shared__ __attribute__((aligned(16))) float xs[64][104];    // halo 10x10 -> 100, pad 104
    __shared__ __attribute__((aligned(16))) float t1s[64][105];   // odd stride: conflict-free conv reads
    __shared__ __attribute__((aligned(16))) float qvs[64][132];   // [pixel][qv-channel], stride 132

    const int tid = threadIdx.x;
    const int blk = blockIdx.x;
    const int b = blk >> 6;          // 4 batches x 64 blocks
    const int bslot = blk & 63;

    // one-time loads
    for (int i = tid; i < 256 * 64; i += NT1) {
        int ch = i >> 6, c = i & 63;
        wT[c][ch] = w_in[i];
    }
    for (int i = tid; i < 128 * 9; i += NT1) {
        int ch = i / 9, k = i - ch * 9;
        wdw_s[ch][k] = w_dw[i];
    }

    // register accumulators (persist across 16 tiles)
    const int gc0 = (tid >> 4) * 2;   // q-channel pair 0..62
    const int gd0 = (tid & 15) * 4;   // v-channel quad 0..60
    float g00 = 0, g01 = 0, g02 = 0, g03 = 0;
    float g10 = 0, g11 = 0, g12 = 0, g13 = 0;
    float sqreg = 0.f;                // tid<128: channel tid of qv

    const float* xb = x + ((size_t)b << 22);

    for (int tIdx = 0; tIdx < 16; ++tIdx) {
        const int tile = bslot + (tIdx << 6);     // 0..1023
        const int ty0 = (tile >> 5) << 3;
        const int tx0 = (tile & 31) << 3;

        __syncthreads();   // protect xs/qvs from previous iteration's readers

        // stage x tile + halo (zero outside image == SAME zero padding of t1)
        for (int i = tid; i < 64 * 104; i += NT1) {
            int c = i / 104;
            int col = i - c * 104;
            float val = 0.f;
            if (col < 100) {
                int py = col / 10;
                int px = col - py * 10;
                int gy = ty0 - 1 + py;
                int gx = tx0 - 1 + px;
                if ((unsigned)gy < 256u && (unsigned)gx < 256u)
                    val = xb[((size_t)c << 16) + (gy << 8) + gx];
            }
            xs[c][col] = val;
        }
        __syncthreads();

        for (int h = 0; h < 2; ++h) {
            // ---- pointwise conv: t1 (64 dw-ch of this half, halo px) + t2 (center px)
            for (int it = tid; it < 672; it += NT1) {
                if (it < 416) {                       // t1: 16 ch-quads x 26 px-quads
                    const int chq = it / 26;
                    const int pq = it - chq * 26;
                    const int ch0 = (h << 6) + (chq << 2);
                    const int p0 = pq << 2;
                    float a00=0,a01=0,a02=0,a03=0, a10=0,a11=0,a12=0,a13=0;
                    float a20=0,a21=0,a22=0,a23=0, a30=0,a31=0,a32=0,a33=0;
                    #pragma unroll 4
                    for (int c = 0; c < 64; ++c) {
                        const float4 wv = *(const float4*)(&wT[c][ch0]);
                        const float4 xv = *(const float4*)(&xs[c][p0]);
                        a00 += wv.x*xv.x; a01 += wv.x*xv.y; a02 += wv.x*xv.z; a03 += wv.x*xv.w;
                        a10 += wv.y*xv.x; a11 += wv.y*xv.y; a12 += wv.y*xv.z; a13 += wv.y*xv.w;
                        a20 += wv.z*xv.x; a21 += wv.z*xv.y; a22 += wv.z*xv.z; a23 += wv.z*xv.w;
                        a30 += wv.w*xv.x; a31 += wv.w*xv.y; a32 += wv.w*xv.z; a33 += wv.w*xv.w;
                    }
                    const int lc = chq << 2;
                    t1s[lc+0][p0+0]=a00; t1s[lc+0][p0+1]=a01; t1s[lc+0][p0+2]=a02; t1s[lc+0][p0+3]=a03;
                    t1s[lc+1][p0+0]=a10; t1s[lc+1][p0+1]=a11; t1s[lc+1][p0+2]=a12; t1s[lc+1][p0+3]=a13;
                    t1s[lc+2][p0+0]=a20; t1s[lc+2][p0+1]=a21; t1s[lc+2][p0+2]=a22; t1s[lc+2][p0+3]=a23;
                    t1s[lc+3][p0+0]=a30; t1s[lc+3][p0+1]=a31; t1s[lc+3][p0+2]=a32; t1s[lc+3][p0+3]=a33;
                } else {                              // t2: 16 ch-quads x 16 center-px-quads
                    const int j = it - 416;
                    const int chq = j >> 4;
                    const int pq = j & 15;
                    const int ch0 = 128 + (h << 6) + (chq << 2);
                    const int p0 = pq << 2;           // center-linear (row of 8 -> same y)
                    const int y = p0 >> 3, xc = p0 & 7;
                    const int hp0 = (y + 1) * 10 + xc + 1;
                    float a00=0,a01=0,a02=0,a03=0, a10=0,a11=0,a12=0,a13=0;
                    float a20=0,a21=0,a22=0,a23=0, a30=0,a31=0,a32=0,a33=0;
                    #pragma unroll 4
                    for (int c = 0; c < 64; ++c) {
                        const float4 wv = *(const float4*)(&wT[c][ch0]);
                        const float x0 = xs[c][hp0+0], x1 = xs[c][hp0+1];
                        const float x2 = xs[c][hp0+2], x3 = xs[c][hp0+3];
                        a00 += wv.x*x0; a01 += wv.x*x1; a02 += wv.x*x2; a03 += wv.x*x3;
                        a10 += wv.y*x0; a11 += wv.y*x1; a12 += wv.y*x2; a13 += wv.y*x3;
                        a20 += wv.z*x0; a21 += wv.z*x1; a22 += wv.z*x2; a23 += wv.z*x3;
                        a30 += wv.w*x0; a31 += wv.w*x1; a32 += wv.w*x2; a33 += wv.w*x3;
                    }
                    const int qc = (h << 6) + (chq << 2);
                    *(float4*)(&qvs[p0+0][qc]) = make_float4(a00, a10, a20, a30);
                    *(float4*)(&qvs[p0+1][qc]) = make_float4(a01, a11, a21, a31);
                    *(float4*)(&qvs[p0+2][qc]) = make_float4(a02, a12, a22, a32);
                    *(float4*)(&qvs[p0+3][qc]) = make_float4(a03, a13, a23, a33);
                }
            }
            __syncthreads();
            // ---- depthwise 3x3 + gate (qv = dw * t2), in-place in qvs
            for (int it = tid; it < 4096; it += NT1) {   // 8 iters exactly
                const int ch = it & 63;
                const int p = it >> 6;
                const int y = p >> 3, xc = p & 7;
                const int base = y * 10 + xc;
                const float* wd = &wdw_s[(h << 6) + ch][0];
                float s = wd[0]*t1s[ch][base+ 0] + wd[1]*t1s[ch][base+ 1] + wd[2]*t1s[ch][base+ 2]
                        + wd[3]*t1s[ch][base+10] + wd[4]*t1s[ch][base+11] + wd[5]*t1s[ch][base+12]
                        + wd[6]*t1s[ch][base+20] + wd[7]*t1s[ch][base+21] + wd[8]*t1s[ch][base+22];
                const int qc = (h << 6) + ch;
                qvs[p][qc] = s * qvs[p][qc];
            }
            __syncthreads();   // before next half overwrites t1s / before G phase
        }

        // ---- G += q.v^T over this tile's 64 pixels (register 2x4 per thread)
        #pragma unroll 4
        for (int p = 0; p < 64; ++p) {
            const float2 q2 = *(const float2*)(&qvs[p][gc0]);
            const float4 v4 = *(const float4*)(&qvs[p][64 + gd0]);
            g00 += q2.x*v4.x; g01 += q2.x*v4.y; g02 += q2.x*v4.z; g03 += q2.x*v4.w;
            g10 += q2.y*v4.x; g11 += q2.y*v4.y; g12 += q2.y*v4.z; g13 += q2.y*v4.w;
        }
        // ---- sum of squares (threads 0..127, channel = tid)
        if (tid < 128) {
            #pragma unroll 8
            for (int p = 0; p < 64; ++p) {
                const float val = qvs[p][tid];
                sqreg += val * val;
            }
        }
        // ---- store v (qv channels 64..127) to global
        for (int it = tid; it < 4096; it += NT1) {
            const int p = it & 63;
            const int d = it >> 6;
            const int gy = ty0 + (p >> 3), gx = tx0 + (p & 7);
            v_out[((size_t)(b * 64 + d) << 16) + (gy << 8) + gx] = qvs[p][64 + d];
        }
    }

    // ---- flush accumulators
    const int gb = b * 4096;
    atomicAdd(&Gacc[gb + (gc0 + 0) * 64 + gd0 + 0], g00);
    atomicAdd(&Gacc[gb + (gc0 + 0) * 64 + gd0 + 1], g01);
    atomicAdd(&Gacc[gb + (gc0 + 0) * 64 + gd0 + 2], g02);
    atomicAdd(&Gacc[gb + (gc0 + 0) * 64 + gd0 + 3], g03);
    atomicAdd(&Gacc[gb + (gc0 + 1) * 64 + gd0 + 0], g10);
    atomicAdd(&Gacc[gb + (gc0 + 1) * 64 + gd0 + 1], g11);
    atomicAdd(&Gacc[gb + (gc0 + 1) * 64 + gd0 + 2], g12);
    atomicAdd(&Gacc[gb + (gc0 + 1) * 64 + gd0 + 3], g13);
    if (tid < 64)       atomicAdd(&sqq[b * 64 + tid], sqreg);
    else if (tid < 128) atomicAdd(&sqv[b * 64 + tid - 64], sqreg);
}

// ---------------------------------------------------------------------------
// Kernel 2: per batch: norms, softmax(G*temp/(|q||v|)), M = w_out @ attn
// Grid: 4 blocks x 256 threads.
// ---------------------------------------------------------------------------
__global__ __launch_bounds__(256)
void k2_softmax(const float* __restrict__ Gacc, const float* __restrict__ sqq,
                const float* __restrict__ sqv, const float* __restrict__ temp,
                const float* __restrict__ w_out, float* __restrict__ M)
{
    __shared__ float attn_s[64][65];
    __shared__ float wo_s[64][65];
    __shared__ float nv_s[64];
    const int b = blockIdx.x, tid = threadIdx.x;

    for (int i = tid; i < 4096; i += 256) {
        int o = i >> 6, c = i & 63;
        wo_s[o][c] = w_out[i];
    }
    if (tid < 64) nv_s[tid] = fmaxf(sqrtf(sqv[b * 64 + tid]), EPSF);
    __syncthreads();

    if (tid < 64) {
        const int c = tid;
        const float nq = fmaxf(sqrtf(sqq[b * 64 + c]), EPSF);
        const float scale = temp[0] / nq;
        float m = -1e30f;
        for (int d = 0; d < 64; ++d) {
            float s = Gacc[b * 4096 + c * 64 + d] / nv_s[d] * scale;
            attn_s[c][d] = s;
            m = fmaxf(m, s);
        }
        float sum = 0.f;
        for (int d = 0; d < 64; ++d) {
            float e = expf(attn_s[c][d] - m);
            attn_s[c][d] = e;
            sum += e;
        }
        const float inv = 1.0f / sum;
        for (int d = 0; d < 64; ++d) attn_s[c][d] *= inv;
    }
    __syncthreads();

    // M[o][d] = sum_c wo[o][c] * attn[c][d]
    const int o = tid & 63, dq = tid >> 6;   // dq: 16 d's each
    float acc[16];
    #pragma unroll
    for (int j = 0; j < 16; ++j) acc[j] = 0.f;
    for (int c = 0; c < 64; ++c) {
        const float wv = wo_s[o][c];
        #pragma unroll
        for (int j = 0; j < 16; ++j) acc[j] += wv * attn_s[c][dq * 16 + j];
    }
    #pragma unroll
    for (int j = 0; j < 16; ++j) M[b * 4096 + o * 64 + dq * 16 + j] = acc[j];
}

// ---------------------------------------------------------------------------
// Kernel 3: out = M @ v, in-place over d_out (each thread reads its v column
// before writing the same column -> no cross-thread hazard).
// Grid: 512 blocks x 256 threads, 2 pixels per thread.
// ---------------------------------------------------------------------------
__global__ __launch_bounds__(256)
void k3_out(const float* __restrict__ M, const float* v, float* out)
{
    __shared__ __attribute__((aligned(16))) float M_s[64][64];
    const int blk = blockIdx.x;
    const int b = blk >> 7;
    const int nb = blk & 127;
    const int tid = threadIdx.x;
    for (int i = tid; i < 4096; i += 256) M_s[i >> 6][i & 63] = M[b * 4096 + i];
    __syncthreads();

    const int n0 = nb * 512 + tid;     // and n0+256
    const float* vb = v + ((size_t)b << 22);
    float* ob = out + ((size_t)b << 22);

    float vr0[64], vr1[64];
    #pragma unroll
    for (int d = 0; d < 64; ++d) {
        vr0[d] = vb[((size_t)d << 16) + n0];
        vr1[d] = vb[((size_t)d << 16) + n0 + 256];
    }
    for (int o = 0; o < 64; ++o) {
        float a0 = 0.f, a1 = 0.f;
        #pragma unroll
        for (int dq = 0; dq < 16; ++dq) {
            const float4 m4 = *(const float4*)(&M_s[o][dq * 4]);
            a0 += m4.x * vr0[dq*4+0]; a1 += m4.x * vr1[dq*4+0];
            a0 += m4.y * vr0[dq*4+1]; a1 += m4.y * vr1[dq*4+1];
            a0 += m4.z * vr0[dq*4+2]; a1 += m4.z * vr1[dq*4+2];
            a0 += m4.w * vr0[dq*4+3]; a1 += m4.w * vr1[dq*4+3];
        }
        ob[((size_t)o << 16) + n0] = a0;
        ob[((size_t)o << 16) + n0 + 256] = a1;
    }
}

// ---------------------------------------------------------------------------
extern "C" void kernel_launch(void* const* d_in, const int* in_sizes, int n_in,
                              void* d_out, int out_size, void* d_ws, size_t ws_size,
                              hipStream_t stream)
{
    (void)in_sizes; (void)n_in; (void)out_size; (void)ws_size;
    const float* x     = (const float*)d_in[0];
    const float* w_in  = (const float*)d_in[1];
    const float* w_dw  = (const float*)d_in[2];
    const float* w_out = (const float*)d_in[3];
    const float* temp  = (const float*)d_in[4];
    float* out = (float*)d_out;

    float* Gacc = (float*)d_ws;          // 16384 floats
    float* sqq  = Gacc + 16384;          // 256
    float* sqv  = sqq + 256;             // 256
    float* Mws  = sqv + 256;             // 16384

    hipMemsetAsync((void*)Gacc, 0, (16384 + 512) * sizeof(float), stream);

    // v lives in d_out (k3 consumes it in-place)
    hipLaunchKernelGGL(k1_fused, dim3(256), dim3(NT1), 0, stream,
                       x, w_in, w_dw, out, Gacc, sqq, sqv);
    hipLaunchKernelGGL(k2_softmax, dim3(4), dim3(256), 0, stream,
                       Gacc, sqq, sqv, temp, w_out, Mws);
    hipLaunchKernelGGL(k3_out, dim3(512), dim3(256), 0, stream,
                       Mws, out, out);
}

// Round 3
// 431.325 us; speedup vs baseline: 1.5337x; 1.5337x over previous
//
#include <hip/hip_runtime.h>

#define EPSF 1e-12f
#define NT1 512

typedef __attribute__((ext_vector_type(8))) short short8;     // MFMA bf16 A/B frag
typedef __attribute__((ext_vector_type(4))) float f32x4;      // MFMA C/D frag
typedef __attribute__((ext_vector_type(4))) unsigned int uint4v;

__device__ __forceinline__ unsigned f2bf(float f) {
    unsigned u = __float_as_uint(f);
    return (u + 0x7FFFu + ((u >> 16) & 1u)) >> 16;
}
__device__ __forceinline__ float bf2f(unsigned h) { return __uint_as_float(h << 16); }
__device__ __forceinline__ short8 asbf(uint4v u) { return __builtin_bit_cast(short8, u); }

// ===========================================================================
// FAST PATH (needs ~192 MiB workspace)
// ===========================================================================

// ---------------------------------------------------------------------------
// kA: x[b][c][px] fp32  ->  xh,xl planes [b][px][64c] bf16 (split hi/lo)
// Grid: 1024 blocks x 256 thr (4 batches x 256 chunks of 256 px)
// ---------------------------------------------------------------------------
__global__ __launch_bounds__(256)
void kA_split(const float* __restrict__ x, unsigned short* __restrict__ xh,
              unsigned short* __restrict__ xl)
{
    __shared__ float xt[64][257];
    const int blk = blockIdx.x, tid = threadIdx.x;
    const int b = blk >> 8, chunk = blk & 255;
    const int px0 = chunk * 256;
    const float* xb = x + ((size_t)b << 22);
    for (int c = 0; c < 64; ++c)
        xt[c][tid] = xb[((size_t)c << 16) + px0 + tid];
    __syncthreads();
    const int px = px0 + tid;
    unsigned hbuf[32], lbuf[32];
    #pragma unroll
    for (int j = 0; j < 32; ++j) {
        float f0 = xt[2*j][tid], f1 = xt[2*j+1][tid];
        unsigned h0 = f2bf(f0), h1 = f2bf(f1);
        float r0 = f0 - bf2f(h0), r1 = f1 - bf2f(h1);
        hbuf[j] = (h1 << 16) | h0;
        lbuf[j] = (f2bf(r1) << 16) | f2bf(r0);
    }
    size_t row = ((size_t)(b << 16) + px) * 64;   // in shorts
    uint4v* dh = (uint4v*)(xh + row);
    uint4v* dl = (uint4v*)(xl + row);
    #pragma unroll
    for (int j = 0; j < 8; ++j) {
        uint4v vh, vl;
        vh[0]=hbuf[4*j]; vh[1]=hbuf[4*j+1]; vh[2]=hbuf[4*j+2]; vh[3]=hbuf[4*j+3];
        vl[0]=lbuf[4*j]; vl[1]=lbuf[4*j+1]; vl[2]=lbuf[4*j+2]; vl[3]=lbuf[4*j+3];
        dh[j] = vh; dl[j] = vl;
    }
}

// ---------------------------------------------------------------------------
// kB: t[b][och][px] (bf16) = w_in[256][64] @ x[64][px], split-bf16 (3 products)
// Grid: 512 blocks x 256 thr (4 waves; wave = och quarter). Block = 512 px.
// ---------------------------------------------------------------------------
__global__ __launch_bounds__(256)
void kB_conv(const unsigned short* __restrict__ xh, const unsigned short* __restrict__ xl,
             const float* __restrict__ w_in, unsigned short* __restrict__ t)
{
    __shared__ float wlds[16384];
    const int tid = threadIdx.x;
    for (int i = tid; i < 16384; i += 256) wlds[i] = w_in[i];
    __syncthreads();
    const int lane = tid & 63, wv = tid >> 6;
    const int l15 = lane & 15, l4 = lane >> 4;

    // A-frags: W hi/lo, 4 och-tiles x 2 k-halves, in registers
    uint4v Ah[4][2], Al[4][2];
    #pragma unroll
    for (int ot = 0; ot < 4; ++ot)
    #pragma unroll
    for (int kh = 0; kh < 2; ++kh) {
        const int och = wv * 64 + ot * 16 + l15;
        const int ich = kh * 32 + l4 * 8;
        const float* wp = &wlds[och * 64 + ich];
        uint4v h, l;
        #pragma unroll
        for (int j = 0; j < 4; ++j) {
            float f0 = wp[2*j], f1 = wp[2*j+1];
            unsigned h0 = f2bf(f0), h1 = f2bf(f1);
            float r0 = f0 - bf2f(h0), r1 = f1 - bf2f(h1);
            h[j] = (h1 << 16) | h0;
            l[j] = (f2bf(r1) << 16) | f2bf(r0);
        }
        Ah[ot][kh] = h; Al[ot][kh] = l;
    }

    const int b = blockIdx.x >> 7;          // 128 blocks per batch
    const int base = blockIdx.x & 127;
    const unsigned short* xhb = xh + (((size_t)b << 16) * 64);
    const unsigned short* xlb = xl + (((size_t)b << 16) * 64);
    unsigned short* tb = t + (((size_t)b << 16) * 256);

    for (int i = 0; i < 32; ++i) {
        const int px0 = (base * 32 + i) * 16;
        const unsigned short* ph = xhb + (size_t)(px0 + l15) * 64 + l4 * 8;
        const unsigned short* pl = xlb + (size_t)(px0 + l15) * 64 + l4 * 8;
        short8 Bh0 = asbf(*(const uint4v*)ph);
        short8 Bh1 = asbf(*(const uint4v*)(ph + 32));
        short8 Bl0 = asbf(*(const uint4v*)pl);
        short8 Bl1 = asbf(*(const uint4v*)(pl + 32));
        f32x4 acc[4];
        #pragma unroll
        for (int ot = 0; ot < 4; ++ot) {
            f32x4 a = {0.f, 0.f, 0.f, 0.f};
            a = __builtin_amdgcn_mfma_f32_16x16x32_bf16(asbf(Ah[ot][0]), Bh0, a, 0, 0, 0);
            a = __builtin_amdgcn_mfma_f32_16x16x32_bf16(asbf(Ah[ot][1]), Bh1, a, 0, 0, 0);
            a = __builtin_amdgcn_mfma_f32_16x16x32_bf16(asbf(Ah[ot][0]), Bl0, a, 0, 0, 0);
            a = __builtin_amdgcn_mfma_f32_16x16x32_bf16(asbf(Ah[ot][1]), Bl1, a, 0, 0, 0);
            a = __builtin_amdgcn_mfma_f32_16x16x32_bf16(asbf(Al[ot][0]), Bh0, a, 0, 0, 0);
            a = __builtin_amdgcn_mfma_f32_16x16x32_bf16(asbf(Al[ot][1]), Bh1, a, 0, 0, 0);
            acc[ot] = a;
        }
        #pragma unroll
        for (int ot = 0; ot < 4; ++ot)
        #pragma unroll
        for (int r = 0; r < 4; ++r) {
            const int och = wv * 64 + ot * 16 + l4 * 4 + r;
            tb[(size_t)och * 65536 + px0 + l15] = (unsigned short)f2bf(acc[ot][r]);
        }
    }
}

// ---------------------------------------------------------------------------
// kC: depthwise 3x3 + gate. Block = (b, ch, 1/8 of image); thread = 8-px strip.
// q -> qh plane (bf16 hi); v -> packed (hi<<16|lo) u32 plane in d_out;
// |q|^2,|v|^2 -> atomics. Grid: 4096 blocks x 256 thr.
// ---------------------------------------------------------------------------
__global__ __launch_bounds__(256)
void kC_dw(const unsigned short* __restrict__ t, const float* __restrict__ w_dw,
           unsigned short* __restrict__ qh, unsigned* __restrict__ vpk,
           float* __restrict__ sqq, float* __restrict__ sqv)
{
    __shared__ float wds[9];
    __shared__ float red[256];
    const int blk = blockIdx.x, tid = threadIdx.x;
    const int bc = blk >> 3, part = blk & 7;
    const int b = bc >> 7, ch = bc & 127;
    if (tid < 9) wds[tid] = w_dw[ch * 9 + tid];
    __syncthreads();
    const float w0 = wds[0], w1 = wds[1], w2 = wds[2];
    const float w3 = wds[3], w4 = wds[4], w5 = wds[5];
    const float w6 = wds[6], w7 = wds[7], w8 = wds[8];
    const unsigned short* t1 = t + (((size_t)b * 256 + ch) << 16);
    const unsigned short* t2 = t + (((size_t)b * 256 + 128 + ch) << 16);
    float sq = 0.f;
    for (int i = 0; i < 4; ++i) {
        const int s = part * 1024 + i * 256 + tid;
        const int y = s >> 5, x0 = (s & 31) << 3;
        float win[3][10];
        #pragma unroll
        for (int r = 0; r < 3; ++r) {
            const int yy = y + r - 1;
            unsigned cen0 = 0, cen1 = 0, cen2 = 0, cen3 = 0, lef = 0, rig = 0;
            if (yy >= 0 && yy < 256) {
                const uint4v cv = *(const uint4v*)(t1 + yy * 256 + x0);
                cen0 = cv[0]; cen1 = cv[1]; cen2 = cv[2]; cen3 = cv[3];
                if (x0 > 0)   lef = *(const unsigned*)(t1 + yy * 256 + x0 - 2);
                if (x0 < 248) rig = *(const unsigned*)(t1 + yy * 256 + x0 + 8);
            }
            win[r][0] = bf2f(lef >> 16);
            win[r][1] = bf2f(cen0 & 0xFFFFu); win[r][2] = bf2f(cen0 >> 16);
            win[r][3] = bf2f(cen1 & 0xFFFFu); win[r][4] = bf2f(cen1 >> 16);
            win[r][5] = bf2f(cen2 & 0xFFFFu); win[r][6] = bf2f(cen2 >> 16);
            win[r][7] = bf2f(cen3 & 0xFFFFu); win[r][8] = bf2f(cen3 >> 16);
            win[r][9] = bf2f(rig & 0xFFFFu);
        }
        const uint4v t2v = *(const uint4v*)(t2 + y * 256 + x0);
        float qv[8];
        #pragma unroll
        for (int k = 0; k < 8; ++k) {
            const float dwv = w0*win[0][k] + w1*win[0][k+1] + w2*win[0][k+2]
                            + w3*win[1][k] + w4*win[1][k+1] + w5*win[1][k+2]
                            + w6*win[2][k] + w7*win[2][k+1] + w8*win[2][k+2];
            const unsigned tu = t2v[k >> 1];
            const float t2f = bf2f((k & 1) ? (tu >> 16) : (tu & 0xFFFFu));
            const float q = dwv * t2f;
            qv[k] = q; sq += q * q;
        }
        const size_t opx = (size_t)y * 256 + x0;
        if (ch < 64) {
            uint4v hp;
            #pragma unroll
            for (int k = 0; k < 4; ++k)
                hp[k] = (f2bf(qv[2*k+1]) << 16) | f2bf(qv[2*k]);
            *(uint4v*)(qh + ((((size_t)b * 64 + ch) << 16) + opx)) = hp;
        } else {
            unsigned vp[8];
            #pragma unroll
            for (int k = 0; k < 8; ++k) {
                const unsigned h = f2bf(qv[k]);
                const float rr = qv[k] - bf2f(h);
                vp[k] = (h << 16) | f2bf(rr);
            }
            unsigned* dst = vpk + ((((size_t)b * 64 + (ch - 64)) << 16) + opx);
            uint4v a, c;
            a[0]=vp[0]; a[1]=vp[1]; a[2]=vp[2]; a[3]=vp[3];
            c[0]=vp[4]; c[1]=vp[5]; c[2]=vp[6]; c[3]=vp[7];
            *(uint4v*)dst = a; *(uint4v*)(dst + 4) = c;
        }
    }
    red[tid] = sq; __syncthreads();
    for (int st = 128; st > 0; st >>= 1) {
        if (tid < st) red[tid] += red[tid + st];
        __syncthreads();
    }
    if (tid == 0)
        atomicAdd((ch < 64) ? &sqq[b * 64 + ch] : &sqv[b * 64 + ch - 64], red[0]);
}

// ---------------------------------------------------------------------------
// kG: G = q @ v^T via MFMA (bf16-hi; error averages out over K=65536).
// Grid: 256 blocks x 256 thr. wave = one 256-px stripe, full 64x64 G.
// ---------------------------------------------------------------------------
__global__ __launch_bounds__(256)
void kG_gemm(const unsigned short* __restrict__ qh, const unsigned* __restrict__ vpk,
             float* __restrict__ Gpart)
{
    const int blk = blockIdx.x, tid = threadIdx.x;
    const int b = blk >> 6, pblk = blk & 63;
    const int lane = tid & 63, wv = tid >> 6;
    const int l15 = lane & 15, l4 = lane >> 4;
    const int stripe = pblk * 4 + wv;       // 0..255
    const int px_base = stripe * 256;
    const unsigned short* qb = qh + ((size_t)b << 22);
    const unsigned* vb = vpk + ((size_t)b << 22);
    f32x4 acc[4][4];
    #pragma unroll
    for (int ct = 0; ct < 4; ++ct)
    #pragma unroll
    for (int dt = 0; dt < 4; ++dt) { f32x4 z = {0.f,0.f,0.f,0.f}; acc[ct][dt] = z; }

    for (int s = 0; s < 8; ++s) {
        const int kofs = px_base + s * 32 + l4 * 8;
        short8 A[4];
        #pragma unroll
        for (int ct = 0; ct < 4; ++ct)
            A[ct] = asbf(*(const uint4v*)(qb + (((size_t)(ct * 16 + l15)) << 16) + kofs));
        #pragma unroll
        for (int dt = 0; dt < 4; ++dt) {
            const unsigned* vp = vb + (((size_t)(dt * 16 + l15)) << 16) + kofs;
            const uint4v u0 = *(const uint4v*)vp;
            const uint4v u1 = *(const uint4v*)(vp + 4);
            uint4v bfv;
            bfv[0] = (u0[1] & 0xFFFF0000u) | (u0[0] >> 16);
            bfv[1] = (u0[3] & 0xFFFF0000u) | (u0[2] >> 16);
            bfv[2] = (u1[1] & 0xFFFF0000u) | (u1[0] >> 16);
            bfv[3] = (u1[3] & 0xFFFF0000u) | (u1[2] >> 16);
            const short8 Bf = asbf(bfv);
            #pragma unroll
            for (int ct = 0; ct < 4; ++ct)
                acc[ct][dt] = __builtin_amdgcn_mfma_f32_16x16x32_bf16(A[ct], Bf, acc[ct][dt], 0, 0, 0);
        }
    }
    float* gp = Gpart + (((size_t)b * 256 + stripe) << 12);
    #pragma unroll
    for (int ct = 0; ct < 4; ++ct)
    #pragma unroll
    for (int dt = 0; dt < 4; ++dt)
    #pragma unroll
    for (int r = 0; r < 4; ++r)
        gp[(ct * 16 + l4 * 4 + r) * 64 + dt * 16 + l15] = acc[ct][dt][r];
}

// ---------------------------------------------------------------------------
// kR: reduce 256 G partials. Grid: 64 blocks x 256 thr (thread per (b,c,d)).
// ---------------------------------------------------------------------------
__global__ __launch_bounds__(256)
void kR_red(const float* __restrict__ Gpart, float* __restrict__ Gred)
{
    const int gid = blockIdx.x * 256 + threadIdx.x;   // 16384
    const int b = gid >> 12, i = gid & 4095;
    float s = 0.f;
    #pragma unroll 8
    for (int p = 0; p < 256; ++p)
        s += Gpart[((((size_t)b * 256) + p) << 12) + i];
    Gred[((size_t)b << 12) + i] = s;
}

// ---------------------------------------------------------------------------
// kD: per batch: norms, softmax(G*temp/(|q||v|)), M = w_out @ attn
// Grid: 4 blocks x 256 threads. (round-1 proven)
// ---------------------------------------------------------------------------
__global__ __launch_bounds__(256)
void kD_softmax(const float* __restrict__ Gred, const float* __restrict__ sqq,
                const float* __restrict__ sqv, const float* __restrict__ temp,
                const float* __restrict__ w_out, float* __restrict__ M)
{
    __shared__ float attn_s[64][65];
    __shared__ float wo_s[64][65];
    __shared__ float nv_s[64];
    const int b = blockIdx.x, tid = threadIdx.x;

    for (int i = tid; i < 4096; i += 256) {
        int o = i >> 6, c = i & 63;
        wo_s[o][c] = w_out[i];
    }
    if (tid < 64) nv_s[tid] = fmaxf(sqrtf(sqv[b * 64 + tid]), EPSF);
    __syncthreads();

    if (tid < 64) {
        const int c = tid;
        const float nq = fmaxf(sqrtf(sqq[b * 64 + c]), EPSF);
        const float scale = temp[0] / nq;
        float m = -1e30f;
        for (int d = 0; d < 64; ++d) {
            float s = Gred[b * 4096 + c * 64 + d] / nv_s[d] * scale;
            attn_s[c][d] = s;
            m = fmaxf(m, s);
        }
        float sum = 0.f;
        for (int d = 0; d < 64; ++d) {
            float e = expf(attn_s[c][d] - m);
            attn_s[c][d] = e;
            sum += e;
        }
        const float inv = 1.0f / sum;
        for (int d = 0; d < 64; ++d) attn_s[c][d] *= inv;
    }
    __syncthreads();

    const int o = tid & 63, dq = tid >> 6;
    float acc[16];
    #pragma unroll
    for (int j = 0; j < 16; ++j) acc[j] = 0.f;
    for (int c = 0; c < 64; ++c) {
        const float wv = wo_s[o][c];
        #pragma unroll
        for (int j = 0; j < 16; ++j) acc[j] += wv * attn_s[c][dq * 16 + j];
    }
    #pragma unroll
    for (int j = 0; j < 16; ++j) M[b * 4096 + o * 64 + dq * 16 + j] = acc[j];
}

// ---------------------------------------------------------------------------
// kE: out = M @ v, in-place over d_out. v stored packed (hi<<16|lo);
// all memory accesses float-typed (aliasing-safe), bit-ops via casts.
// Grid: 512 blocks x 256 thr, 2 px/thread.
// ---------------------------------------------------------------------------
__global__ __launch_bounds__(256)
void kE_out(const float* __restrict__ M, float* vout)
{
    __shared__ __attribute__((aligned(16))) float M_s[64][64];
    const int blk = blockIdx.x;
    const int b = blk >> 7, nb = blk & 127;
    const int tid = threadIdx.x;
    for (int i = tid; i < 4096; i += 256) M_s[i >> 6][i & 63] = M[b * 4096 + i];
    __syncthreads();

    const int n0 = nb * 512 + tid;
    float* vb = vout + ((size_t)b << 22);

    float vr0[64], vr1[64];
    #pragma unroll
    for (int d = 0; d < 64; ++d) {
        const unsigned u0 = __float_as_uint(vb[((size_t)d << 16) + n0]);
        const unsigned u1 = __float_as_uint(vb[((size_t)d << 16) + n0 + 256]);
        vr0[d] = __uint_as_float(u0 & 0xFFFF0000u) + __uint_as_float(u0 << 16);
        vr1[d] = __uint_as_float(u1 & 0xFFFF0000u) + __uint_as_float(u1 << 16);
    }
    for (int o = 0; o < 64; ++o) {
        float a0 = 0.f, a1 = 0.f;
        #pragma unroll
        for (int dq = 0; dq < 16; ++dq) {
            const float4 m4 = *(const float4*)(&M_s[o][dq * 4]);
            a0 += m4.x * vr0[dq*4+0]; a1 += m4.x * vr1[dq*4+0];
            a0 += m4.y * vr0[dq*4+1]; a1 += m4.y * vr1[dq*4+1];
            a0 += m4.z * vr0[dq*4+2]; a1 += m4.z * vr1[dq*4+2];
            a0 += m4.w * vr0[dq*4+3]; a1 += m4.w * vr1[dq*4+3];
        }
        vb[((size_t)o << 16) + n0] = a0;
        vb[((size_t)o << 16) + n0 + 256] = a1;
    }
}

// ===========================================================================
// FALLBACK PATH — round-1 kernels (proven: 661us, absmax 3e-5)
// ===========================================================================
__global__ __launch_bounds__(NT1)
void k1_fused(const float* __restrict__ x, const float* __restrict__ w_in,
              const float* __restrict__ w_dw, float* __restrict__ v_out,
              float* __restrict__ Gacc, float* __restrict__ sqq,
              float* __restrict__ sqv)
{
    __shared__ __attribute__((aligned(16))) float wT[64][256];
    __shared__ __attribute__((aligned(16))) float wdw_s[128][11];
    __shared__ __attribute__((aligned(16))) float xs[64][104];
    __shared__ __attribute__((aligned(16))) float t1s[64][105];
    __shared__ __attribute__((aligned(16))) float qvs[64][132];

    const int tid = threadIdx.x;
    const int blk = blockIdx.x;
    const int b = blk >> 6;
    const int bslot = blk & 63;

    for (int i = tid; i < 256 * 64; i += NT1) {
        int ch = i >> 6, c = i & 63;
        wT[c][ch] = w_in[i];
    }
    for (int i = tid; i < 128 * 9; i += NT1) {
        int ch = i / 9, k = i - ch * 9;
        wdw_s[ch][k] = w_dw[i];
    }

    const int gc0 = (tid >> 4) * 2;
    const int gd0 = (tid & 15) * 4;
    float g00 = 0, g01 = 0, g02 = 0, g03 = 0;
    float g10 = 0, g11 = 0, g12 = 0, g13 = 0;
    float sqreg = 0.f;

    const float* xb = x + ((size_t)b << 22);

    for (int tIdx = 0; tIdx < 16; ++tIdx) {
        const int tile = bslot + (tIdx << 6);
        const int ty0 = (tile >> 5) << 3;
        const int tx0 = (tile & 31) << 3;

        __syncthreads();

        for (int i = tid; i < 64 * 104; i += NT1) {
            int c = i / 104;
            int col = i - c * 104;
            float val = 0.f;
            if (col < 100) {
                int py = col / 10;
                int px = col - py * 10;
                int gy = ty0 - 1 + py;
                int gx = tx0 - 1 + px;
                if ((unsigned)gy < 256u && (unsigned)gx < 256u)
                    val = xb[((size_t)c << 16) + (gy << 8) + gx];
            }
            xs[c][col] = val;
        }
        __syncthreads();

        for (int h = 0; h < 2; ++h) {
            for (int it = tid; it < 672; it += NT1) {
                if (it < 416) {
                    const int chq = it / 26;
                    const int pq = it - chq * 26;
                    const int ch0 = (h << 6) + (chq << 2);
                    const int p0 = pq << 2;
                    float a00=0,a01=0,a02=0,a03=0, a10=0,a11=0,a12=0,a13=0;
                    float a20=0,a21=0,a22=0,a23=0, a30=0,a31=0,a32=0,a33=0;
                    #pragma unroll 4
                    for (int c = 0; c < 64; ++c) {
                        const float4 wv = *(const float4*)(&wT[c][ch0]);
                        const float4 xv = *(const float4*)(&xs[c][p0]);
                        a00 += wv.x*xv.x; a01 += wv.x*xv.y; a02 += wv.x*xv.z; a03 += wv.x*xv.w;
                        a10 += wv.y*xv.x; a11 += wv.y*xv.y; a12 += wv.y*xv.z; a13 += wv.y*xv.w;
                        a20 += wv.z*xv.x; a21 += wv.z*xv.y; a22 += wv.z*xv.z; a23 += wv.z*xv.w;
                        a30 += wv.w*xv.x; a31 += wv.w*xv.y; a32 += wv.w*xv.z; a33 += wv.w*xv.w;
                    }
                    const int lc = chq << 2;
                    t1s[lc+0][p0+0]=a00; t1s[lc+0][p0+1]=a01; t1s[lc+0][p0+2]=a02; t1s[lc+0][p0+3]=a03;
                    t1s[lc+1][p0+0]=a10; t1s[lc+1][p0+1]=a11; t1s[lc+1][p0+2]=a12; t1s[lc+1][p0+3]=a13;
                    t1s[lc+2][p0+0]=a20; t1s[lc+2][p0+1]=a21; t1s[lc+2][p0+2]=a22; t1s[lc+2][p0+3]=a23;
                    t1s[lc+3][p0+0]=a30; t1s[lc+3][p0+1]=a31; t1s[lc+3][p0+2]=a32; t1s[lc+3][p0+3]=a33;
                } else {
                    const int j = it - 416;
                    const int chq = j >> 4;
                    const int pq = j & 15;
                    const int ch0 = 128 + (h << 6) + (chq << 2);
                    const int p0 = pq << 2;
                    const int y = p0 >> 3, xc = p0 & 7;
                    const int hp0 = (y + 1) * 10 + xc + 1;
                    float a00=0,a01=0,a02=0,a03=0, a10=0,a11=0,a12=0,a13=0;
                    float a20=0,a21=0,a22=0,a23=0, a30=0,a31=0,a32=0,a33=0;
                    #pragma unroll 4
                    for (int c = 0; c < 64; ++c) {
                        const float4 wv = *(const float4*)(&wT[c][ch0]);
                        const float x0 = xs[c][hp0+0], x1 = xs[c][hp0+1];
                        const float x2 = xs[c][hp0+2], x3 = xs[c][hp0+3];
                        a00 += wv.x*x0; a01 += wv.x*x1; a02 += wv.x*x2; a03 += wv.x*x3;
                        a10 += wv.y*x0; a11 += wv.y*x1; a12 += wv.y*x2; a13 += wv.y*x3;
                        a20 += wv.z*x0; a21 += wv.z*x1; a22 += wv.z*x2; a23 += wv.z*x3;
                        a30 += wv.w*x0; a31 += wv.w*x1; a32 += wv.w*x2; a33 += wv.w*x3;
                    }
                    const int qc = (h << 6) + (chq << 2);
                    *(float4*)(&qvs[p0+0][qc]) = make_float4(a00, a10, a20, a30);
                    *(float4*)(&qvs[p0+1][qc]) = make_float4(a01, a11, a21, a31);
                    *(float4*)(&qvs[p0+2][qc]) = make_float4(a02, a12, a22, a32);
                    *(float4*)(&qvs[p0+3][qc]) = make_float4(a03, a13, a23, a33);
                }
            }
            __syncthreads();
            for (int it = tid; it < 4096; it += NT1) {
                const int ch = it & 63;
                const int p = it >> 6;
                const int y = p >> 3, xc = p & 7;
                const int base = y * 10 + xc;
                const float* wd = &wdw_s[(h << 6) + ch][0];
                float s = wd[0]*t1s[ch][base+ 0] + wd[1]*t1s[ch][base+ 1] + wd[2]*t1s[ch][base+ 2]
                        + wd[3]*t1s[ch][base+10] + wd[4]*t1s[ch][base+11] + wd[5]*t1s[ch][base+12]
                        + wd[6]*t1s[ch][base+20] + wd[7]*t1s[ch][base+21] + wd[8]*t1s[ch][base+22];
                const int qc = (h << 6) + ch;
                qvs[p][qc] = s * qvs[p][qc];
            }
            __syncthreads();
        }

        #pragma unroll 4
        for (int p = 0; p < 64; ++p) {
            const float2 q2 = *(const float2*)(&qvs[p][gc0]);
            const float4 v4 = *(const float4*)(&qvs[p][64 + gd0]);
            g00 += q2.x*v4.x; g01 += q2.x*v4.y; g02 += q2.x*v4.z; g03 += q2.x*v4.w;
            g10 += q2.y*v4.x; g11 += q2.y*v4.y; g12 += q2.y*v4.z; g13 += q2.y*v4.w;
        }
        if (tid < 128) {
            #pragma unroll 8
            for (int p = 0; p < 64; ++p) {
                const float val = qvs[p][tid];
                sqreg += val * val;
            }
        }
        for (int it = tid; it < 4096; it += NT1) {
            const int p = it & 63;
            const int d = it >> 6;
            const int gy = ty0 + (p >> 3), gx = tx0 + (p & 7);
            v_out[((size_t)(b * 64 + d) << 16) + (gy << 8) + gx] = qvs[p][64 + d];
        }
    }

    const int gb = b * 4096;
    atomicAdd(&Gacc[gb + (gc0 + 0) * 64 + gd0 + 0], g00);
    atomicAdd(&Gacc[gb + (gc0 + 0) * 64 + gd0 + 1], g01);
    atomicAdd(&Gacc[gb + (gc0 + 0) * 64 + gd0 + 2], g02);
    atomicAdd(&Gacc[gb + (gc0 + 0) * 64 + gd0 + 3], g03);
    atomicAdd(&Gacc[gb + (gc0 + 1) * 64 + gd0 + 0], g10);
    atomicAdd(&Gacc[gb + (gc0 + 1) * 64 + gd0 + 1], g11);
    atomicAdd(&Gacc[gb + (gc0 + 1) * 64 + gd0 + 2], g12);
    atomicAdd(&Gacc[gb + (gc0 + 1) * 64 + gd0 + 3], g13);
    if (tid < 64)       atomicAdd(&sqq[b * 64 + tid], sqreg);
    else if (tid < 128) atomicAdd(&sqv[b * 64 + tid - 64], sqreg);
}

__global__ __launch_bounds__(256)
void k3_out(const float* __restrict__ M, const float* v, float* out)
{
    __shared__ __attribute__((aligned(16))) float M_s[64][64];
    const int blk = blockIdx.x;
    const int b = blk >> 7;
    const int nb = blk & 127;
    const int tid = threadIdx.x;
    for (int i = tid; i < 4096; i += 256) M_s[i >> 6][i & 63] = M[b * 4096 + i];
    __syncthreads();

    const int n0 = nb * 512 + tid;
    const float* vb = v + ((size_t)b << 22);
    float* ob = out + ((size_t)b << 22);

    float vr0[64], vr1[64];
    #pragma unroll
    for (int d = 0; d < 64; ++d) {
        vr0[d] = vb[((size_t)d << 16) + n0];
        vr1[d] = vb[((size_t)d << 16) + n0 + 256];
    }
    for (int o = 0; o < 64; ++o) {
        float a0 = 0.f, a1 = 0.f;
        #pragma unroll
        for (int dq = 0; dq < 16; ++dq) {
            const float4 m4 = *(const float4*)(&M_s[o][dq * 4]);
            a0 += m4.x * vr0[dq*4+0]; a1 += m4.x * vr1[dq*4+0];
            a0 += m4.y * vr0[dq*4+1]; a1 += m4.y * vr1[dq*4+1];
            a0 += m4.z * vr0[dq*4+2]; a1 += m4.z * vr1[dq*4+2];
            a0 += m4.w * vr0[dq*4+3]; a1 += m4.w * vr1[dq*4+3];
        }
        ob[((size_t)o << 16) + n0] = a0;
        ob[((size_t)o << 16) + n0 + 256] = a1;
    }
}

// ===========================================================================
extern "C" void kernel_launch(void* const* d_in, const int* in_sizes, int n_in,
                              void* d_out, int out_size, void* d_ws, size_t ws_size,
                              hipStream_t stream)
{
    (void)in_sizes; (void)n_in; (void)out_size;
    const float* x     = (const float*)d_in[0];
    const float* w_in  = (const float*)d_in[1];
    const float* w_dw  = (const float*)d_in[2];
    const float* w_out = (const float*)d_in[3];
    const float* temp  = (const float*)d_in[4];
    float* out = (float*)d_out;

    // fast-path workspace layout (bytes); qh overlays xh and Gpart overlays xl
    // after kB completes (stream-ordered).
    const size_t OFF_T     = 0;                     // 134217728 (t bf16)
    const size_t OFF_XH    = 134217728;             // 33554432
    const size_t OFF_XL    = 167772160;             // 33554432
    const size_t OFF_QH    = OFF_XH;                // overlay (33554432)
    const size_t OFF_GPART = OFF_XL;                // overlay (16777216)
    const size_t OFF_GRED  = 201326592;             // 65536
    const size_t OFF_SQQ   = 201392128;             // 1024
    const size_t OFF_SQV   = 201393152;             // 1024
    const size_t OFF_M     = 201394176;             // 65536
    const size_t NEED      = 201459712;             // ~192.2 MiB

    if (ws_size >= NEED) {
        char* ws = (char*)d_ws;
        unsigned short* t   = (unsigned short*)(ws + OFF_T);
        unsigned short* xh  = (unsigned short*)(ws + OFF_XH);
        unsigned short* xl  = (unsigned short*)(ws + OFF_XL);
        unsigned short* qh  = (unsigned short*)(ws + OFF_QH);
        float* Gpart = (float*)(ws + OFF_GPART);
        float* Gred  = (float*)(ws + OFF_GRED);
        float* sqq   = (float*)(ws + OFF_SQQ);
        float* sqv   = (float*)(ws + OFF_SQV);
        float* Mws   = (float*)(ws + OFF_M);

        hipMemsetAsync((void*)sqq, 0, 2048, stream);
        hipLaunchKernelGGL(kA_split, dim3(1024), dim3(256), 0, stream, x, xh, xl);
        hipLaunchKernelGGL(kB_conv, dim3(512), dim3(256), 0, stream, xh, xl, w_in, t);
        hipLaunchKernelGGL(kC_dw, dim3(4096), dim3(256), 0, stream,
                           t, w_dw, qh, (unsigned*)d_out, sqq, sqv);
        hipLaunchKernelGGL(kG_gemm, dim3(256), dim3(256), 0, stream,
                           qh, (const unsigned*)d_out, Gpart);
        hipLaunchKernelGGL(kR_red, dim3(64), dim3(256), 0, stream, Gpart, Gred);
        hipLaunchKernelGGL(kD_softmax, dim3(4), dim3(256), 0, stream,
                           Gred, sqq, sqv, temp, w_out, Mws);
        hipLaunchKernelGGL(kE_out, dim3(512), dim3(256), 0, stream, Mws, out);
    } else {
        // fallback: round-1 path (~133 KiB ws)
        float* Gacc = (float*)d_ws;
        float* sqq  = Gacc + 16384;
        float* sqv  = sqq + 256;
        float* Mws  = sqv + 256;
        hipMemsetAsync((void*)Gacc, 0, (16384 + 512) * sizeof(float), stream);
        hipLaunchKernelGGL(k1_fused, dim3(256), dim3(NT1), 0, stream,
                           x, w_in, w_dw, out, Gacc, sqq, sqv);
        hipLaunchKernelGGL(kD_softmax, dim3(4), dim3(256), 0, stream,
                           Gacc, sqq, sqv, temp, w_out, Mws);
        hipLaunchKernelGGL(k3_out, dim3(512), dim3(256), 0, stream,
                           Mws, out, out);
    }
}